// Round 1
// baseline (706.952 us; speedup 1.0000x reference)
//
#include <hip/hip_runtime.h>
#include <hip/hip_bf16.h>

typedef __hip_bfloat16 bf16;
typedef __bf16 bf16x8 __attribute__((ext_vector_type(8)));
typedef float f32x4 __attribute__((ext_vector_type(4)));

#define B_ 4
#define S_ 4096
#define D_ 1024
#define BS_ 16384   // B*S
#define N3_ 3072    // 3*D

__device__ __forceinline__ void gld_lds16(const void* g, void* l) {
    __builtin_amdgcn_global_load_lds(
        (const __attribute__((address_space(1))) void*)g,
        (__attribute__((address_space(3))) void*)l, 16, 0, 0);
}

__device__ __forceinline__ void cast4_one(const float* __restrict__ in,
                                          bf16* __restrict__ out, int i) {
    float4 v = ((const float4*)in)[i];
    union { ushort4 u; bf16 h[4]; } cv;
    cv.h[0] = __float2bfloat16(v.x);
    cv.h[1] = __float2bfloat16(v.y);
    cv.h[2] = __float2bfloat16(v.z);
    cv.h[3] = __float2bfloat16(v.w);
    ((ushort4*)out)[i] = cv.u;
}

// ---- fused prologue: all casts + bias concat + rowsum zero in ONE dispatch ----
__global__ __launch_bounds__(256) void prologue(
    const float* __restrict__ x, const float* __restrict__ wq,
    const float* __restrict__ wk, const float* __restrict__ wv,
    const float* __restrict__ wo, const float* __restrict__ bq,
    const float* __restrict__ bk, const float* __restrict__ bv,
    bf16* __restrict__ xb, bf16* __restrict__ Wc, bf16* __restrict__ Wo,
    float* __restrict__ bc, float* __restrict__ ls) {
    const int blk = blockIdx.x, tid = threadIdx.x;
    if (blk < 16384) {                      // x: 16384*1024/4 float4 chunks
        cast4_one(x, xb, blk * 256 + tid);
    } else if (blk < 20480) {               // 4 weights, 1024 blocks each
        int w = (blk - 16384) >> 10;
        int i = ((blk - 16384) & 1023) * 256 + tid;
        const float* src = (w == 0) ? wq : (w == 1) ? wk : (w == 2) ? wv : wo;
        bf16* dst = (w == 3) ? Wo : Wc + (long)w * D_ * D_;
        cast4_one(src, dst, i);
    } else if (blk < 20544) {               // zero rowsums (16384 floats)
        ls[(blk - 20480) * 256 + tid] = 0.f;
    } else {                                // bias concat (3072)
        for (int i = tid; i < N3_; i += 256)
            bc[i] = (i < 1024) ? bq[i] : (i < 2048) ? bk[i - 1024] : bv[i - 2048];
    }
}

// ---------------- V transpose: per batch, V (4096 x 1024 strided in QKV) -> VT (1024 x 4096)
__global__ __launch_bounds__(256) void transpose_v(const bf16* __restrict__ QKV,
                                                   bf16* __restrict__ VT) {
    __shared__ bf16 t[32][33];
    const int b = blockIdx.z;
    const bf16* Vb = QKV + (long)b * S_ * N3_ + 2048;
    bf16* VTb = VT + (long)b * D_ * S_;
    const int s0 = blockIdx.x * 32, d0 = blockIdx.y * 32;
    const int r = threadIdx.x >> 5, c = threadIdx.x & 31;
#pragma unroll
    for (int i = 0; i < 4; i++)
        t[r + i * 8][c] = Vb[(long)(s0 + r + i * 8) * N3_ + d0 + c];
    __syncthreads();
#pragma unroll
    for (int i = 0; i < 4; i++)
        VTb[(long)(d0 + r + i * 8) * S_ + s0 + c] = t[c][r + i * 8];
}

// ---------------- legacy 128-tile NT GEMM (kept for tier-0/1 fallback paths) ----
template <int EPI, int BM>
__global__ __launch_bounds__(256, 2) void gemm_nt(
    const bf16* __restrict__ A, int lda, long sA,
    const bf16* __restrict__ B, int ldb, long sB,
    void* __restrict__ Cout, int ldc, long sC,
    int K, const float* __restrict__ bias,
    float* __restrict__ rowsum, int sL, float scale) {
    constexpr int MI = BM / 32;
    __shared__ __align__(16) bf16 As[BM * 64];
    __shared__ __align__(16) bf16 Bs[128 * 64];
    const int tid = threadIdx.x;
    const int lane = tid & 63;
    const int wave = tid >> 6;
    const int bz = blockIdx.z;
    const int m0 = blockIdx.x * BM, n0 = blockIdx.y * 128;
    A += (long)bz * sA;
    B += (long)bz * sB;
    rowsum += (long)bz * sL;

    const int wr = (wave >> 1) * (BM / 2);
    const int wc = (wave & 1) * 64;
    const int fm = lane & 15;
    const int q4 = lane >> 4;
    const int sw = fm & 7;
    const int rd0 = ((q4 ^ sw) << 3);
    const int rd1 = (((4 + q4) ^ sw) << 3);

    f32x4 zero = {0.f, 0.f, 0.f, 0.f};
    f32x4 acc[MI][4];
#pragma unroll
    for (int i = 0; i < MI; i++)
#pragma unroll
        for (int j = 0; j < 4; j++) acc[i][j] = zero;

    for (int k0 = 0; k0 < K; k0 += 64) {
#pragma unroll
        for (int t = 0; t < BM / 32; t++) {
            int c = tid + t * 256;
            int row = c >> 3;
            int q = (((c & 7) ^ (row & 7)) << 3);
            gld_lds16(A + (long)(m0 + row) * lda + k0 + q, As + c * 8);
        }
#pragma unroll
        for (int t = 0; t < 4; t++) {
            int c = tid + t * 256;
            int row = c >> 3;
            int q = (((c & 7) ^ (row & 7)) << 3);
            gld_lds16(B + (long)(n0 + row) * ldb + k0 + q, Bs + c * 8);
        }
        __syncthreads();
#pragma unroll
        for (int kh = 0; kh < 2; kh++) {
            const int rdo = kh ? rd1 : rd0;
            bf16x8 af[MI], bfr[4];
#pragma unroll
            for (int i = 0; i < MI; i++)
                af[i] = *(const bf16x8*)(As + (wr + i * 16 + fm) * 64 + rdo);
#pragma unroll
            for (int j = 0; j < 4; j++)
                bfr[j] = *(const bf16x8*)(Bs + (wc + j * 16 + fm) * 64 + rdo);
#pragma unroll
            for (int i = 0; i < MI; i++)
#pragma unroll
                for (int j = 0; j < 4; j++)
                    acc[i][j] = __builtin_amdgcn_mfma_f32_16x16x32_bf16(
                        af[i], bfr[j], acc[i][j], 0, 0, 0);
        }
        __syncthreads();
    }

#pragma unroll
    for (int i = 0; i < MI; i++)
#pragma unroll
        for (int r = 0; r < 4; r++) {
            const int grow = m0 + wr + q4 * 4 + i * 16 + r;
            if constexpr (EPI == 0) {
#pragma unroll
                for (int j = 0; j < 4; j++) {
                    int gcol = n0 + wc + j * 16 + fm;
                    ((bf16*)Cout)[(long)bz * sC + (long)grow * ldc + gcol] =
                        __float2bfloat16(acc[i][j][r] + bias[gcol]);
                }
            } else if constexpr (EPI == 1) {
                float s = 0.f;
#pragma unroll
                for (int j = 0; j < 4; j++) {
                    int gcol = n0 + wc + j * 16 + fm;
                    float v = __expf(acc[i][j][r] * scale);
                    bf16 hv = __float2bfloat16(v);
                    ((bf16*)Cout)[(long)bz * sC + (long)grow * ldc + gcol] = hv;
                    s += __bfloat162float(hv);
                }
                s += __shfl_xor(s, 1, 16);
                s += __shfl_xor(s, 2, 16);
                s += __shfl_xor(s, 4, 16);
                s += __shfl_xor(s, 8, 16);
                if (fm == 0) atomicAdd(rowsum + grow, s);
            } else if constexpr (EPI == 2) {
                float inv = 1.0f / rowsum[grow];
#pragma unroll
                for (int j = 0; j < 4; j++) {
                    int gcol = n0 + wc + j * 16 + fm;
                    ((bf16*)Cout)[(long)bz * sC + (long)grow * ldc + gcol] =
                        __float2bfloat16(acc[i][j][r] * inv);
                }
            } else {
#pragma unroll
                for (int j = 0; j < 4; j++) {
                    int gcol = n0 + wc + j * 16 + fm;
                    ((float*)Cout)[(long)bz * sC + (long)grow * ldc + gcol] =
                        acc[i][j][r] + bias[gcol];
                }
            }
        }
}

// ======================================================================
// 256x256 8-phase pipelined NT GEMM (T3+T4 counted vmcnt + T5 setprio).
// K-split half-tiles (256x32) make the counted waits race-free:
//   tile t phases 1-2 consume kh0 only, 3-4 consume kh1 only, so tile t+1
//   can start with its kh1 halves still in flight. 2 LDS buffers, 128 KiB.
// Per-thread in flight: up to 8 gld_lds (4 half-tiles); vmcnt(4) twice per
// K-tile, vmcnt(0) only in the peeled last tile.
// LDS rows are 64B (32 bf16): frag reads are bank-balanced without swizzle
// ((fm&1) row parity x q4 slot covers all 32 banks at 8 words/bank).
// ======================================================================
__device__ __forceinline__ void stage_half(const bf16* __restrict__ g, int ld,
                                           bf16* l, int tid) {
#pragma unroll
    for (int t = 0; t < 2; t++) {
        const int ch = tid + t * 512;                  // 1024 chunks of 16B
        gld_lds16(g + (long)(ch >> 2) * ld + ((ch & 3) << 3), l + ch * 8);
    }
    asm volatile("" ::: "memory");  // pin issue order vs counted s_waitcnt
}

__device__ __forceinline__ void ds_a4(bf16x8 (&d)[4], const bf16* base, int ro,
                                      int wr, int fm, int q4) {
#pragma unroll
    for (int i = 0; i < 4; i++)
        d[i] = *(const bf16x8*)(base + (wr + ro + i * 16 + fm) * 32 + (q4 << 3));
}

__device__ __forceinline__ void ds_b4(bf16x8 (&d)[4], const bf16* base,
                                      int wc, int fm, int q4) {
#pragma unroll
    for (int j = 0; j < 4; j++)
        d[j] = *(const bf16x8*)(base + (wc + j * 16 + fm) * 32 + (q4 << 3));
}

template <int IO>
__device__ __forceinline__ void mfma16(f32x4 (&acc)[8][4], const bf16x8 (&a)[4],
                                       const bf16x8 (&b)[4]) {
    __builtin_amdgcn_s_setprio(1);
#pragma unroll
    for (int i = 0; i < 4; i++)
#pragma unroll
        for (int j = 0; j < 4; j++)
            acc[IO + i][j] = __builtin_amdgcn_mfma_f32_16x16x32_bf16(
                a[i], b[j], acc[IO + i][j], 0, 0, 0);
    __builtin_amdgcn_s_setprio(0);
}

#define BAR() __builtin_amdgcn_s_barrier()
#define LGKM0() asm volatile("s_waitcnt lgkmcnt(0)" ::: "memory")
#define VM4() asm volatile("s_waitcnt vmcnt(4)" ::: "memory")
#define VM0() asm volatile("s_waitcnt vmcnt(0)" ::: "memory")

template <int EPI>
__global__ __launch_bounds__(512, 2) void gemm8(
    const bf16* __restrict__ A, int lda, long sA,
    const bf16* __restrict__ B, int ldb, long sB,
    void* __restrict__ Cout, int ldc, long sC,
    int K, const float* __restrict__ bias,
    float* __restrict__ rowsum, int sL, float scale) {
    __shared__ __align__(16) bf16 As[2][2][256 * 32];   // [buf][khalf] 64 KiB
    __shared__ __align__(16) bf16 Bs[2][2][256 * 32];   // 64 KiB
    const int tid = threadIdx.x;
    const int lane = tid & 63;
    const int wave = tid >> 6;
    const int bz = blockIdx.z;
    const int m0 = blockIdx.x * 256, n0 = blockIdx.y * 256;
    A += (long)bz * sA + (long)m0 * lda;
    B += (long)bz * sB + (long)n0 * ldb;
    rowsum += (long)bz * sL;

    const int wm = wave >> 2, wn = wave & 3;   // 2M x 4N waves
    const int wr = wm * 128, wc = wn * 64;     // per-wave C block 128x64
    const int fm = lane & 15, q4 = lane >> 4;

    f32x4 zero = {0.f, 0.f, 0.f, 0.f};
    f32x4 acc[8][4];
#pragma unroll
    for (int i = 0; i < 8; i++)
#pragma unroll
        for (int j = 0; j < 4; j++) acc[i][j] = zero;

    const int NT = K >> 6;
    // prologue: tile 0 (A-kh0, B-kh0, A-kh1, B-kh1); wait kh0 (oldest 4 loads)
    stage_half(A, lda, &As[0][0][0], tid);
    stage_half(B, ldb, &Bs[0][0][0], tid);
    stage_half(A + 32, lda, &As[0][1][0], tid);
    stage_half(B + 32, ldb, &Bs[0][1][0], tid);
    VM4();
    BAR();

    bf16x8 a[4], b[4];
    for (int t = 0; t + 1 < NT; ++t) {
        const int c = t & 1, n = c ^ 1;
        const int kn = (t + 1) << 6;
        // P1: kh0, M-frags 0-3; prefetch A-kh0(t+1)
        ds_a4(a, &As[c][0][0], 0, wr, fm, q4);
        ds_b4(b, &Bs[c][0][0], wc, fm, q4);
        stage_half(A + kn, lda, &As[n][0][0], tid);
        BAR(); LGKM0();
        mfma16<0>(acc, a, b);
        BAR();
        // P2: kh0, M-frags 4-7 (b reused); prefetch B-kh0(t+1)
        ds_a4(a, &As[c][0][0], 64, wr, fm, q4);
        stage_half(B + kn, ldb, &Bs[n][0][0], tid);
        BAR(); LGKM0();
        mfma16<4>(acc, a, b);
        VM4();   // kh1(t) landed; kh0(t+1) (4 loads) stays in flight
        BAR();
        // P3: kh1, M-frags 0-3; prefetch A-kh1(t+1)
        ds_a4(a, &As[c][1][0], 0, wr, fm, q4);
        ds_b4(b, &Bs[c][1][0], wc, fm, q4);
        stage_half(A + kn + 32, lda, &As[n][1][0], tid);
        BAR(); LGKM0();
        mfma16<0>(acc, a, b);
        BAR();
        // P4: kh1, M-frags 4-7; prefetch B-kh1(t+1)
        ds_a4(a, &As[c][1][0], 64, wr, fm, q4);
        stage_half(B + kn + 32, ldb, &Bs[n][1][0], tid);
        BAR(); LGKM0();
        mfma16<4>(acc, a, b);
        VM4();   // kh0(t+1) landed; kh1(t+1) (4 loads) stays in flight
        BAR();
    }
    {   // peeled last tile: no prefetch; drain kh1 before phases 3-4
        const int c = (NT - 1) & 1;
        ds_a4(a, &As[c][0][0], 0, wr, fm, q4);
        ds_b4(b, &Bs[c][0][0], wc, fm, q4);
        BAR(); LGKM0();
        mfma16<0>(acc, a, b);
        BAR();
        ds_a4(a, &As[c][0][0], 64, wr, fm, q4);
        BAR(); LGKM0();
        mfma16<4>(acc, a, b);
        VM0();
        BAR();
        ds_a4(a, &As[c][1][0], 0, wr, fm, q4);
        ds_b4(b, &Bs[c][1][0], wc, fm, q4);
        BAR(); LGKM0();
        mfma16<0>(acc, a, b);
        BAR();
        ds_a4(a, &As[c][1][0], 64, wr, fm, q4);
        BAR(); LGKM0();
        mfma16<4>(acc, a, b);
    }

    // C/D layout: col = lane&15, row = (lane>>4)*4 + reg  [m89/m91]
#pragma unroll
    for (int mi = 0; mi < 8; mi++)
#pragma unroll
        for (int r = 0; r < 4; r++) {
            const int grow = m0 + wr + mi * 16 + q4 * 4 + r;
            if constexpr (EPI == 0) {
#pragma unroll
                for (int j = 0; j < 4; j++) {
                    int gcol = n0 + wc + j * 16 + fm;
                    ((bf16*)Cout)[(long)bz * sC + (long)grow * ldc + gcol] =
                        __float2bfloat16(acc[mi][j][r] + bias[gcol]);
                }
            } else if constexpr (EPI == 1) {
                float s = 0.f;
#pragma unroll
                for (int j = 0; j < 4; j++) {
                    int gcol = n0 + wc + j * 16 + fm;
                    float v = __expf(acc[mi][j][r] * scale);
                    bf16 hv = __float2bfloat16(v);
                    ((bf16*)Cout)[(long)bz * sC + (long)grow * ldc + gcol] = hv;
                    s += __bfloat162float(hv);  // sum what we actually stored
                }
                s += __shfl_xor(s, 1, 16);
                s += __shfl_xor(s, 2, 16);
                s += __shfl_xor(s, 4, 16);
                s += __shfl_xor(s, 8, 16);
                if (fm == 0) atomicAdd(rowsum + grow, s);
            } else if constexpr (EPI == 2) {
                float inv = 1.0f / rowsum[grow];
#pragma unroll
                for (int j = 0; j < 4; j++) {
                    int gcol = n0 + wc + j * 16 + fm;
                    ((bf16*)Cout)[(long)bz * sC + (long)grow * ldc + gcol] =
                        __float2bfloat16(acc[mi][j][r] * inv);
                }
            } else {
#pragma unroll
                for (int j = 0; j < 4; j++) {
                    int gcol = n0 + wc + j * 16 + fm;
                    ((float*)Cout)[(long)bz * sC + (long)grow * ldc + gcol] =
                        acc[mi][j][r] + bias[gcol];
                }
            }
        }
}

extern "C" void kernel_launch(void* const* d_in, const int* in_sizes, int n_in,
                              void* d_out, int out_size, void* d_ws, size_t ws_size,
                              hipStream_t stream) {
    const float* x  = (const float*)d_in[0];
    const float* wq = (const float*)d_in[1];
    const float* bq = (const float*)d_in[2];
    const float* wk = (const float*)d_in[3];
    const float* bk = (const float*)d_in[4];
    const float* wv = (const float*)d_in[5];
    const float* bv = (const float*)d_in[6];
    const float* wo = (const float*)d_in[7];
    const float* bo = (const float*)d_in[8];
    (void)in_sizes; (void)n_in; (void)out_size;

    // base ws carve: 104.07 MiB (proven to fit)
    char* p = (char*)d_ws;
    bf16* Wc  = (bf16*)p;  p += (long)N3_ * D_ * 2;   // 6 MiB
    bf16* Wo  = (bf16*)p;  p += (long)D_ * D_ * 2;    // 2 MiB
    float* bc = (float*)p; p += N3_ * 4;              // 12 KiB
    bf16* QKV = (bf16*)p;  p += (long)BS_ * N3_ * 2;  // 96 MiB; Q cols become At
    float* ls = (float*)p; p += (long)BS_ * 4;        // 64 KiB

    bf16* xb = (bf16*)d_out;                          // 32 MiB; dead after QKV GEMM

    const size_t base = 109129728UL;
    int tier;
    bf16 *VT, *E;
    if (ws_size >= base + 134217728UL) {
        tier = 2;
        E  = (bf16*)p;
        VT = (bf16*)((char*)d_out + 33554432);
    } else if (ws_size >= base + 33554432UL) {
        tier = 1;
        VT = (bf16*)p;
        E  = (bf16*)d_out;
    } else {
        tier = 0;
        VT = (bf16*)((char*)d_out + 33554432);
        E  = (bf16*)d_out;
    }

    // 1) fused prologue
    prologue<<<dim3(20545), 256, 0, stream>>>(x, wq, wk, wv, wo, bq, bk, bv,
                                              xb, Wc, Wo, bc, ls);

    // 2) QKV = xb @ Wc^T + bc  (M=16384, N=3072, K=1024) — 256^2 8-phase
    gemm8<0><<<dim3(BS_ / 256, N3_ / 256, 1), 512, 0, stream>>>(
        xb, D_, 0, Wc, D_, 0, QKV, N3_, 0, D_, bc, ls, 0, 1.f);

    // 3) VT[b][d][s] = V[b][s][d]
    transpose_v<<<dim3(S_ / 32, D_ / 32, B_), 256, 0, stream>>>(QKV, VT);

    // 4) attention: E = exp(QK^T/32) (+rowsum), At = (E V)/rowsum -> Q region
    if (tier == 2) {
        gemm8<1><<<dim3(16, 16, 4), 512, 0, stream>>>(
            QKV, N3_, (long)S_ * N3_, QKV + 1024, N3_, (long)S_ * N3_,
            E, S_, (long)S_ * S_, D_, nullptr, ls, S_, 0.03125f);
        gemm8<2><<<dim3(16, 4, 4), 512, 0, stream>>>(
            E, S_, (long)S_ * S_, VT, S_, (long)D_ * S_,
            QKV, N3_, (long)S_ * N3_, S_, nullptr, ls, S_, 1.f);
    } else if (tier == 1) {
        for (int pr = 0; pr < 2; ++pr) {
            const long qoff = (long)(2 * pr) * S_ * N3_;
            gemm_nt<1, 128><<<dim3(32, 32, 2), 256, 0, stream>>>(
                QKV + qoff, N3_, (long)S_ * N3_,
                QKV + qoff + 1024, N3_, (long)S_ * N3_,
                E, S_, (long)S_ * S_, D_, nullptr, ls + 2 * pr * S_, S_, 0.03125f);
            gemm_nt<2, 128><<<dim3(32, 8, 2), 256, 0, stream>>>(
                E, S_, (long)S_ * S_,
                VT + (long)(2 * pr) * D_ * S_, S_, (long)D_ * S_,
                QKV + qoff, N3_, (long)S_ * N3_, S_, nullptr, ls + 2 * pr * S_, S_, 1.f);
        }
    } else {
        for (int b = 0; b < B_; ++b) {
            const long qoff = (long)b * S_ * N3_;
            gemm_nt<1, 128><<<dim3(32, 32, 1), 256, 0, stream>>>(
                QKV + qoff, N3_, 0, QKV + qoff + 1024, N3_, 0,
                E, S_, 0, D_, nullptr, ls + b * S_, 0, 0.03125f);
            gemm_nt<2, 64><<<dim3(64, 8, 1), 256, 0, stream>>>(
                E, S_, 0, VT + (long)b * D_ * S_, S_, 0,
                QKV + qoff, N3_, 0, S_, nullptr, ls + b * S_, 0, 1.f);
        }
    }

    // 5) out = At @ Wo^T + bo -> fp32  (M=16384, N=1024, K=1024)
    gemm8<3><<<dim3(BS_ / 256, D_ / 256, 1), 512, 0, stream>>>(
        QKV, N3_, 0, Wo, D_, 0, d_out, D_, 0, D_, bo, ls, 0, 1.f);
}

// Round 2
// 685.612 us; speedup vs baseline: 1.0311x; 1.0311x over previous
//
#include <hip/hip_runtime.h>
#include <hip/hip_bf16.h>

typedef __hip_bfloat16 bf16;
typedef __bf16 bf16x8 __attribute__((ext_vector_type(8)));
typedef float f32x4 __attribute__((ext_vector_type(4)));

#define B_ 4
#define S_ 4096
#define D_ 1024
#define BS_ 16384   // B*S
#define N3_ 3072    // 3*D

__device__ __forceinline__ void gld_lds16(const void* g, void* l) {
    __builtin_amdgcn_global_load_lds(
        (const __attribute__((address_space(1))) void*)g,
        (__attribute__((address_space(3))) void*)l, 16, 0, 0);
}

__device__ __forceinline__ void cast4_one(const float* __restrict__ in,
                                          bf16* __restrict__ out, int i) {
    float4 v = ((const float4*)in)[i];
    union { ushort4 u; bf16 h[4]; } cv;
    cv.h[0] = __float2bfloat16(v.x);
    cv.h[1] = __float2bfloat16(v.y);
    cv.h[2] = __float2bfloat16(v.z);
    cv.h[3] = __float2bfloat16(v.w);
    ((ushort4*)out)[i] = cv.u;
}

// ---- fused prologue: all casts + bias concat + rowsum zero in ONE dispatch ----
__global__ __launch_bounds__(256) void prologue(
    const float* __restrict__ x, const float* __restrict__ wq,
    const float* __restrict__ wk, const float* __restrict__ wv,
    const float* __restrict__ wo, const float* __restrict__ bq,
    const float* __restrict__ bk, const float* __restrict__ bv,
    bf16* __restrict__ xb, bf16* __restrict__ Wc, bf16* __restrict__ Wo,
    float* __restrict__ bc, float* __restrict__ ls) {
    const int blk = blockIdx.x, tid = threadIdx.x;
    if (blk < 16384) {                      // x: 16384*1024/4 float4 chunks
        cast4_one(x, xb, blk * 256 + tid);
    } else if (blk < 20480) {               // 4 weights, 1024 blocks each
        int w = (blk - 16384) >> 10;
        int i = ((blk - 16384) & 1023) * 256 + tid;
        const float* src = (w == 0) ? wq : (w == 1) ? wk : (w == 2) ? wv : wo;
        bf16* dst = (w == 3) ? Wo : Wc + (long)w * D_ * D_;
        cast4_one(src, dst, i);
    } else if (blk < 20544) {               // zero rowsums (16384 floats)
        ls[(blk - 20480) * 256 + tid] = 0.f;
    } else {                                // bias concat (3072)
        for (int i = tid; i < N3_; i += 256)
            bc[i] = (i < 1024) ? bq[i] : (i < 2048) ? bk[i - 1024] : bv[i - 2048];
    }
}

// ---------------- V transpose: per batch, V (4096 x 1024 strided in QKV) -> VT (1024 x 4096)
__global__ __launch_bounds__(256) void transpose_v(const bf16* __restrict__ QKV,
                                                   bf16* __restrict__ VT) {
    __shared__ bf16 t[32][33];
    const int b = blockIdx.z;
    const bf16* Vb = QKV + (long)b * S_ * N3_ + 2048;
    bf16* VTb = VT + (long)b * D_ * S_;
    const int s0 = blockIdx.x * 32, d0 = blockIdx.y * 32;
    const int r = threadIdx.x >> 5, c = threadIdx.x & 31;
#pragma unroll
    for (int i = 0; i < 4; i++)
        t[r + i * 8][c] = Vb[(long)(s0 + r + i * 8) * N3_ + d0 + c];
    __syncthreads();
#pragma unroll
    for (int i = 0; i < 4; i++)
        VTb[(long)(d0 + r + i * 8) * S_ + s0 + c] = t[c][r + i * 8];
}

// ---------------- legacy 128-tile NT GEMM (kept for tier-0/1 fallback paths) ----
template <int EPI, int BM>
__global__ __launch_bounds__(256, 2) void gemm_nt(
    const bf16* __restrict__ A, int lda, long sA,
    const bf16* __restrict__ B, int ldb, long sB,
    void* __restrict__ Cout, int ldc, long sC,
    int K, const float* __restrict__ bias,
    float* __restrict__ rowsum, int sL, float scale) {
    constexpr int MI = BM / 32;
    __shared__ __align__(16) bf16 As[BM * 64];
    __shared__ __align__(16) bf16 Bs[128 * 64];
    const int tid = threadIdx.x;
    const int lane = tid & 63;
    const int wave = tid >> 6;
    const int bz = blockIdx.z;
    const int m0 = blockIdx.x * BM, n0 = blockIdx.y * 128;
    A += (long)bz * sA;
    B += (long)bz * sB;
    rowsum += (long)bz * sL;

    const int wr = (wave >> 1) * (BM / 2);
    const int wc = (wave & 1) * 64;
    const int fm = lane & 15;
    const int q4 = lane >> 4;
    const int sw = fm & 7;
    const int rd0 = ((q4 ^ sw) << 3);
    const int rd1 = (((4 + q4) ^ sw) << 3);

    f32x4 zero = {0.f, 0.f, 0.f, 0.f};
    f32x4 acc[MI][4];
#pragma unroll
    for (int i = 0; i < MI; i++)
#pragma unroll
        for (int j = 0; j < 4; j++) acc[i][j] = zero;

    for (int k0 = 0; k0 < K; k0 += 64) {
#pragma unroll
        for (int t = 0; t < BM / 32; t++) {
            int c = tid + t * 256;
            int row = c >> 3;
            int q = (((c & 7) ^ (row & 7)) << 3);
            gld_lds16(A + (long)(m0 + row) * lda + k0 + q, As + c * 8);
        }
#pragma unroll
        for (int t = 0; t < 4; t++) {
            int c = tid + t * 256;
            int row = c >> 3;
            int q = (((c & 7) ^ (row & 7)) << 3);
            gld_lds16(B + (long)(n0 + row) * ldb + k0 + q, Bs + c * 8);
        }
        __syncthreads();
#pragma unroll
        for (int kh = 0; kh < 2; kh++) {
            const int rdo = kh ? rd1 : rd0;
            bf16x8 af[MI], bfr[4];
#pragma unroll
            for (int i = 0; i < MI; i++)
                af[i] = *(const bf16x8*)(As + (wr + i * 16 + fm) * 64 + rdo);
#pragma unroll
            for (int j = 0; j < 4; j++)
                bfr[j] = *(const bf16x8*)(Bs + (wc + j * 16 + fm) * 64 + rdo);
#pragma unroll
            for (int i = 0; i < MI; i++)
#pragma unroll
                for (int j = 0; j < 4; j++)
                    acc[i][j] = __builtin_amdgcn_mfma_f32_16x16x32_bf16(
                        af[i], bfr[j], acc[i][j], 0, 0, 0);
        }
        __syncthreads();
    }

#pragma unroll
    for (int i = 0; i < MI; i++)
#pragma unroll
        for (int r = 0; r < 4; r++) {
            const int grow = m0 + wr + q4 * 4 + i * 16 + r;
            if constexpr (EPI == 0) {
#pragma unroll
                for (int j = 0; j < 4; j++) {
                    int gcol = n0 + wc + j * 16 + fm;
                    ((bf16*)Cout)[(long)bz * sC + (long)grow * ldc + gcol] =
                        __float2bfloat16(acc[i][j][r] + bias[gcol]);
                }
            } else if constexpr (EPI == 1) {
                float s = 0.f;
#pragma unroll
                for (int j = 0; j < 4; j++) {
                    int gcol = n0 + wc + j * 16 + fm;
                    float v = __expf(acc[i][j][r] * scale);
                    bf16 hv = __float2bfloat16(v);
                    ((bf16*)Cout)[(long)bz * sC + (long)grow * ldc + gcol] = hv;
                    s += __bfloat162float(hv);
                }
                s += __shfl_xor(s, 1, 16);
                s += __shfl_xor(s, 2, 16);
                s += __shfl_xor(s, 4, 16);
                s += __shfl_xor(s, 8, 16);
                if (fm == 0) atomicAdd(rowsum + grow, s);
            } else if constexpr (EPI == 2) {
                float inv = 1.0f / rowsum[grow];
#pragma unroll
                for (int j = 0; j < 4; j++) {
                    int gcol = n0 + wc + j * 16 + fm;
                    ((bf16*)Cout)[(long)bz * sC + (long)grow * ldc + gcol] =
                        __float2bfloat16(acc[i][j][r] * inv);
                }
            } else {
#pragma unroll
                for (int j = 0; j < 4; j++) {
                    int gcol = n0 + wc + j * 16 + fm;
                    ((float*)Cout)[(long)bz * sC + (long)grow * ldc + gcol] =
                        acc[i][j][r] + bias[gcol];
                }
            }
        }
}

// ======================================================================
// 256x256 8-phase pipelined NT GEMM (T3+T4 counted vmcnt + T5 setprio).
// K-split half-tiles (256x32): tile t phases 1-2 consume kh0 only, 3-4
// consume kh1 only, so tile t+1 starts with its kh1 halves in flight.
// 2 LDS buffers, 128 KiB; vmcnt(4) twice per K-tile, vmcnt(0) only in the
// peeled last tile.
// LDS swizzle (r1 fix; r0 had 8-way conflicts, 12.6M cycles): slot =
// chunk ^ ((row>>1)&3). Within any 16-lane group, (row&1, slot) is a
// bijection onto 8 bank-groups -> 2 lanes/bank = free [m136]. Store side
// keeps LDS dest linear (gld_lds requirement) and pre-swizzles the GLOBAL
// source chunk (rule #21) — permutation stays inside each row's 64B, so
// coalescing is intact. Read offset is a per-thread constant.
// ======================================================================
__device__ __forceinline__ void stage_half(const bf16* __restrict__ g, int ld,
                                           bf16* l, int tid) {
#pragma unroll
    for (int t = 0; t < 2; t++) {
        const int ch = tid + t * 512;                  // 1024 chunks of 16B
        const int row = ch >> 2;
        const int q = (ch ^ (row >> 1)) & 3;           // inverse swizzle on src
        gld_lds16(g + (long)row * ld + (q << 3), l + ch * 8);
    }
    asm volatile("" ::: "memory");  // pin issue order vs counted s_waitcnt
}

__device__ __forceinline__ void ds_a4(bf16x8 (&d)[4], const bf16* base, int ro,
                                      int wr, int fm, int rdo) {
#pragma unroll
    for (int i = 0; i < 4; i++)
        d[i] = *(const bf16x8*)(base + (wr + ro + i * 16 + fm) * 32 + rdo);
}

__device__ __forceinline__ void ds_b4(bf16x8 (&d)[4], const bf16* base,
                                      int wc, int fm, int rdo) {
#pragma unroll
    for (int j = 0; j < 4; j++)
        d[j] = *(const bf16x8*)(base + (wc + j * 16 + fm) * 32 + rdo);
}

template <int IO>
__device__ __forceinline__ void mfma16(f32x4 (&acc)[8][4], const bf16x8 (&a)[4],
                                       const bf16x8 (&b)[4]) {
    __builtin_amdgcn_s_setprio(1);
#pragma unroll
    for (int i = 0; i < 4; i++)
#pragma unroll
        for (int j = 0; j < 4; j++)
            acc[IO + i][j] = __builtin_amdgcn_mfma_f32_16x16x32_bf16(
                a[i], b[j], acc[IO + i][j], 0, 0, 0);
    __builtin_amdgcn_s_setprio(0);
}

#define BAR() __builtin_amdgcn_s_barrier()
#define LGKM0() asm volatile("s_waitcnt lgkmcnt(0)" ::: "memory")
#define VM4() asm volatile("s_waitcnt vmcnt(4)" ::: "memory")
#define VM0() asm volatile("s_waitcnt vmcnt(0)" ::: "memory")

template <int EPI>
__global__ __launch_bounds__(512, 2) void gemm8(
    const bf16* __restrict__ A, int lda, long sA,
    const bf16* __restrict__ B, int ldb, long sB,
    void* __restrict__ Cout, int ldc, long sC,
    int K, const float* __restrict__ bias,
    float* __restrict__ rowsum, int sL, float scale) {
    __shared__ __align__(16) bf16 As[2][2][256 * 32];   // [buf][khalf] 64 KiB
    __shared__ __align__(16) bf16 Bs[2][2][256 * 32];   // 64 KiB
    const int tid = threadIdx.x;
    const int lane = tid & 63;
    const int wave = tid >> 6;
    const int bz = blockIdx.z;
    const int m0 = blockIdx.x * 256, n0 = blockIdx.y * 256;
    A += (long)bz * sA + (long)m0 * lda;
    B += (long)bz * sB + (long)n0 * ldb;
    rowsum += (long)bz * sL;

    const int wm = wave >> 2, wn = wave & 3;   // 2M x 4N waves
    const int wr = wm * 128, wc = wn * 64;     // per-wave C block 128x64
    const int fm = lane & 15, q4 = lane >> 4;
    // slot = q4 ^ ((row>>1)&3); wr/ro/i*16 are all 0 mod 4 after >>1,
    // so the swizzled read offset is a per-thread constant.
    const int rdo = ((q4 ^ ((fm >> 1) & 3)) << 3);

    f32x4 zero = {0.f, 0.f, 0.f, 0.f};
    f32x4 acc[8][4];
#pragma unroll
    for (int i = 0; i < 8; i++)
#pragma unroll
        for (int j = 0; j < 4; j++) acc[i][j] = zero;

    const int NT = K >> 6;
    // prologue: tile 0 (A-kh0, B-kh0, A-kh1, B-kh1); wait kh0 (oldest 4 loads)
    stage_half(A, lda, &As[0][0][0], tid);
    stage_half(B, ldb, &Bs[0][0][0], tid);
    stage_half(A + 32, lda, &As[0][1][0], tid);
    stage_half(B + 32, ldb, &Bs[0][1][0], tid);
    VM4();
    BAR();

    bf16x8 a[4], b[4];
    for (int t = 0; t + 1 < NT; ++t) {
        const int c = t & 1, n = c ^ 1;
        const int kn = (t + 1) << 6;
        // P1: kh0, M-frags 0-3; prefetch A-kh0(t+1)
        ds_a4(a, &As[c][0][0], 0, wr, fm, rdo);
        ds_b4(b, &Bs[c][0][0], wc, fm, rdo);
        stage_half(A + kn, lda, &As[n][0][0], tid);
        BAR(); LGKM0();
        mfma16<0>(acc, a, b);
        BAR();
        // P2: kh0, M-frags 4-7 (b reused); prefetch B-kh0(t+1)
        ds_a4(a, &As[c][0][0], 64, wr, fm, rdo);
        stage_half(B + kn, ldb, &Bs[n][0][0], tid);
        BAR(); LGKM0();
        mfma16<4>(acc, a, b);
        VM4();   // kh1(t) landed; kh0(t+1) (4 loads) stays in flight
        BAR();
        // P3: kh1, M-frags 0-3; prefetch A-kh1(t+1)
        ds_a4(a, &As[c][1][0], 0, wr, fm, rdo);
        ds_b4(b, &Bs[c][1][0], wc, fm, rdo);
        stage_half(A + kn + 32, lda, &As[n][1][0], tid);
        BAR(); LGKM0();
        mfma16<0>(acc, a, b);
        BAR();
        // P4: kh1, M-frags 4-7; prefetch B-kh1(t+1)
        ds_a4(a, &As[c][1][0], 64, wr, fm, rdo);
        stage_half(B + kn + 32, ldb, &Bs[n][1][0], tid);
        BAR(); LGKM0();
        mfma16<4>(acc, a, b);
        VM4();   // kh0(t+1) landed; kh1(t+1) (4 loads) stays in flight
        BAR();
    }
    {   // peeled last tile: no prefetch; drain kh1 before phases 3-4
        const int c = (NT - 1) & 1;
        ds_a4(a, &As[c][0][0], 0, wr, fm, rdo);
        ds_b4(b, &Bs[c][0][0], wc, fm, rdo);
        BAR(); LGKM0();
        mfma16<0>(acc, a, b);
        BAR();
        ds_a4(a, &As[c][0][0], 64, wr, fm, rdo);
        BAR(); LGKM0();
        mfma16<4>(acc, a, b);
        VM0();
        BAR();
        ds_a4(a, &As[c][1][0], 0, wr, fm, rdo);
        ds_b4(b, &Bs[c][1][0], wc, fm, rdo);
        BAR(); LGKM0();
        mfma16<0>(acc, a, b);
        BAR();
        ds_a4(a, &As[c][1][0], 64, wr, fm, rdo);
        BAR(); LGKM0();
        mfma16<4>(acc, a, b);
    }

    // C/D layout: col = lane&15, row = (lane>>4)*4 + reg  [m89/m91]
#pragma unroll
    for (int mi = 0; mi < 8; mi++)
#pragma unroll
        for (int r = 0; r < 4; r++) {
            const int grow = m0 + wr + mi * 16 + q4 * 4 + r;
            if constexpr (EPI == 0) {
#pragma unroll
                for (int j = 0; j < 4; j++) {
                    int gcol = n0 + wc + j * 16 + fm;
                    ((bf16*)Cout)[(long)bz * sC + (long)grow * ldc + gcol] =
                        __float2bfloat16(acc[mi][j][r] + bias[gcol]);
                }
            } else if constexpr (EPI == 1) {
                float s = 0.f;
#pragma unroll
                for (int j = 0; j < 4; j++) {
                    int gcol = n0 + wc + j * 16 + fm;
                    float v = __expf(acc[mi][j][r] * scale);
                    bf16 hv = __float2bfloat16(v);
                    ((bf16*)Cout)[(long)bz * sC + (long)grow * ldc + gcol] = hv;
                    s += __bfloat162float(hv);  // sum what we actually stored
                }
                s += __shfl_xor(s, 1, 16);
                s += __shfl_xor(s, 2, 16);
                s += __shfl_xor(s, 4, 16);
                s += __shfl_xor(s, 8, 16);
                if (fm == 0) atomicAdd(rowsum + grow, s);
            } else if constexpr (EPI == 2) {
                float inv = 1.0f / rowsum[grow];
#pragma unroll
                for (int j = 0; j < 4; j++) {
                    int gcol = n0 + wc + j * 16 + fm;
                    ((bf16*)Cout)[(long)bz * sC + (long)grow * ldc + gcol] =
                        __float2bfloat16(acc[mi][j][r] * inv);
                }
            } else {
#pragma unroll
                for (int j = 0; j < 4; j++) {
                    int gcol = n0 + wc + j * 16 + fm;
                    ((float*)Cout)[(long)bz * sC + (long)grow * ldc + gcol] =
                        acc[mi][j][r] + bias[gcol];
                }
            }
        }
}

extern "C" void kernel_launch(void* const* d_in, const int* in_sizes, int n_in,
                              void* d_out, int out_size, void* d_ws, size_t ws_size,
                              hipStream_t stream) {
    const float* x  = (const float*)d_in[0];
    const float* wq = (const float*)d_in[1];
    const float* bq = (const float*)d_in[2];
    const float* wk = (const float*)d_in[3];
    const float* bk = (const float*)d_in[4];
    const float* wv = (const float*)d_in[5];
    const float* bv = (const float*)d_in[6];
    const float* wo = (const float*)d_in[7];
    const float* bo = (const float*)d_in[8];
    (void)in_sizes; (void)n_in; (void)out_size;

    // base ws carve: 104.07 MiB (proven to fit)
    char* p = (char*)d_ws;
    bf16* Wc  = (bf16*)p;  p += (long)N3_ * D_ * 2;   // 6 MiB
    bf16* Wo  = (bf16*)p;  p += (long)D_ * D_ * 2;    // 2 MiB
    float* bc = (float*)p; p += N3_ * 4;              // 12 KiB
    bf16* QKV = (bf16*)p;  p += (long)BS_ * N3_ * 2;  // 96 MiB; Q cols become At
    float* ls = (float*)p; p += (long)BS_ * 4;        // 64 KiB

    bf16* xb = (bf16*)d_out;                          // 32 MiB; dead after QKV GEMM

    const size_t base = 109129728UL;
    int tier;
    bf16 *VT, *E;
    if (ws_size >= base + 134217728UL) {
        tier = 2;
        E  = (bf16*)p;
        VT = (bf16*)((char*)d_out + 33554432);
    } else if (ws_size >= base + 33554432UL) {
        tier = 1;
        VT = (bf16*)p;
        E  = (bf16*)d_out;
    } else {
        tier = 0;
        VT = (bf16*)((char*)d_out + 33554432);
        E  = (bf16*)d_out;
    }

    // 1) fused prologue
    prologue<<<dim3(20545), 256, 0, stream>>>(x, wq, wk, wv, wo, bq, bk, bv,
                                              xb, Wc, Wo, bc, ls);

    // 2) QKV = xb @ Wc^T + bc  (M=16384, N=3072, K=1024) — 256^2 8-phase
    gemm8<0><<<dim3(BS_ / 256, N3_ / 256, 1), 512, 0, stream>>>(
        xb, D_, 0, Wc, D_, 0, QKV, N3_, 0, D_, bc, ls, 0, 1.f);

    // 3) VT[b][d][s] = V[b][s][d]
    transpose_v<<<dim3(S_ / 32, D_ / 32, B_), 256, 0, stream>>>(QKV, VT);

    // 4) attention: E = exp(QK^T/32) (+rowsum), At = (E V)/rowsum -> Q region
    if (tier == 2) {
        gemm8<1><<<dim3(16, 16, 4), 512, 0, stream>>>(
            QKV, N3_, (long)S_ * N3_, QKV + 1024, N3_, (long)S_ * N3_,
            E, S_, (long)S_ * S_, D_, nullptr, ls, S_, 0.03125f);
        gemm8<2><<<dim3(16, 4, 4), 512, 0, stream>>>(
            E, S_, (long)S_ * S_, VT, S_, (long)D_ * S_,
            QKV, N3_, (long)S_ * N3_, S_, nullptr, ls, S_, 1.f);
    } else if (tier == 1) {
        for (int pr = 0; pr < 2; ++pr) {
            const long qoff = (long)(2 * pr) * S_ * N3_;
            gemm_nt<1, 128><<<dim3(32, 32, 2), 256, 0, stream>>>(
                QKV + qoff, N3_, (long)S_ * N3_,
                QKV + qoff + 1024, N3_, (long)S_ * N3_,
                E, S_, (long)S_ * S_, D_, nullptr, ls + 2 * pr * S_, S_, 0.03125f);
            gemm_nt<2, 128><<<dim3(32, 8, 2), 256, 0, stream>>>(
                E, S_, (long)S_ * S_,
                VT + (long)(2 * pr) * D_ * S_, S_, (long)D_ * S_,
                QKV + qoff, N3_, (long)S_ * N3_, S_, nullptr, ls + 2 * pr * S_, S_, 1.f);
        }
    } else {
        for (int b = 0; b < B_; ++b) {
            const long qoff = (long)b * S_ * N3_;
            gemm_nt<1, 128><<<dim3(32, 32, 1), 256, 0, stream>>>(
                QKV + qoff, N3_, 0, QKV + qoff + 1024, N3_, 0,
                E, S_, 0, D_, nullptr, ls + b * S_, 0, 0.03125f);
            gemm_nt<2, 64><<<dim3(64, 8, 1), 256, 0, stream>>>(
                E, S_, 0, VT + (long)b * D_ * S_, S_, 0,
                QKV + qoff, N3_, 0, S_, nullptr, ls + b * S_, 0, 1.f);
        }
    }

    // 5) out = At @ Wo^T + bo -> fp32  (M=16384, N=1024, K=1024)
    gemm8<3><<<dim3(BS_ / 256, D_ / 256, 1), 512, 0, stream>>>(
        QKV, N3_, 0, Wo, D_, 0, d_out, D_, 0, D_, bo, ls, 0, 1.f);
}

// Round 3
// 635.279 us; speedup vs baseline: 1.1128x; 1.0792x over previous
//
#include <hip/hip_runtime.h>
#include <hip/hip_bf16.h>

typedef __hip_bfloat16 bf16;
typedef __bf16 bf16x8 __attribute__((ext_vector_type(8)));
typedef float f32x4 __attribute__((ext_vector_type(4)));

#define B_ 4
#define S_ 4096
#define D_ 1024
#define BS_ 16384   // B*S
#define N3_ 3072    // 3*D

__device__ __forceinline__ void gld_lds16(const void* g, void* l) {
    __builtin_amdgcn_global_load_lds(
        (const __attribute__((address_space(1))) void*)g,
        (__attribute__((address_space(3))) void*)l, 16, 0, 0);
}

__device__ __forceinline__ void cast4_one(const float* __restrict__ in,
                                          bf16* __restrict__ out, int i) {
    float4 v = ((const float4*)in)[i];
    union { ushort4 u; bf16 h[4]; } cv;
    cv.h[0] = __float2bfloat16(v.x);
    cv.h[1] = __float2bfloat16(v.y);
    cv.h[2] = __float2bfloat16(v.z);
    cv.h[3] = __float2bfloat16(v.w);
    ((ushort4*)out)[i] = cv.u;
}

// ---- fused prologue: all casts + bias concat + rowsum zero in ONE dispatch ----
__global__ __launch_bounds__(256) void prologue(
    const float* __restrict__ x, const float* __restrict__ wq,
    const float* __restrict__ wk, const float* __restrict__ wv,
    const float* __restrict__ wo, const float* __restrict__ bq,
    const float* __restrict__ bk, const float* __restrict__ bv,
    bf16* __restrict__ xb, bf16* __restrict__ Wc, bf16* __restrict__ Wo,
    float* __restrict__ bc, float* __restrict__ ls) {
    const int blk = blockIdx.x, tid = threadIdx.x;
    if (blk < 16384) {                      // x: 16384*1024/4 float4 chunks
        cast4_one(x, xb, blk * 256 + tid);
    } else if (blk < 20480) {               // 4 weights, 1024 blocks each
        int w = (blk - 16384) >> 10;
        int i = ((blk - 16384) & 1023) * 256 + tid;
        const float* src = (w == 0) ? wq : (w == 1) ? wk : (w == 2) ? wv : wo;
        bf16* dst = (w == 3) ? Wo : Wc + (long)w * D_ * D_;
        cast4_one(src, dst, i);
    } else if (blk < 20544) {               // zero rowsums (16384 floats)
        ls[(blk - 20480) * 256 + tid] = 0.f;
    } else {                                // bias concat (3072)
        for (int i = tid; i < N3_; i += 256)
            bc[i] = (i < 1024) ? bq[i] : (i < 2048) ? bk[i - 1024] : bv[i - 2048];
    }
}

// ---------------- V transpose: per batch, V (4096 x 1024 strided in QKV) -> VT (1024 x 4096)
__global__ __launch_bounds__(256) void transpose_v(const bf16* __restrict__ QKV,
                                                   bf16* __restrict__ VT) {
    __shared__ bf16 t[32][33];
    const int b = blockIdx.z;
    const bf16* Vb = QKV + (long)b * S_ * N3_ + 2048;
    bf16* VTb = VT + (long)b * D_ * S_;
    const int s0 = blockIdx.x * 32, d0 = blockIdx.y * 32;
    const int r = threadIdx.x >> 5, c = threadIdx.x & 31;
#pragma unroll
    for (int i = 0; i < 4; i++)
        t[r + i * 8][c] = Vb[(long)(s0 + r + i * 8) * N3_ + d0 + c];
    __syncthreads();
#pragma unroll
    for (int i = 0; i < 4; i++)
        VTb[(long)(d0 + r + i * 8) * S_ + s0 + c] = t[c][r + i * 8];
}

// ---------------- legacy 128-tile NT GEMM (kept for tier-0/1 fallback paths) ----
template <int EPI, int BM>
__global__ __launch_bounds__(256, 2) void gemm_nt(
    const bf16* __restrict__ A, int lda, long sA,
    const bf16* __restrict__ B, int ldb, long sB,
    void* __restrict__ Cout, int ldc, long sC,
    int K, const float* __restrict__ bias,
    float* __restrict__ rowsum, int sL, float scale) {
    constexpr int MI = BM / 32;
    __shared__ __align__(16) bf16 As[BM * 64];
    __shared__ __align__(16) bf16 Bs[128 * 64];
    const int tid = threadIdx.x;
    const int lane = tid & 63;
    const int wave = tid >> 6;
    const int bz = blockIdx.z;
    const int m0 = blockIdx.x * BM, n0 = blockIdx.y * 128;
    A += (long)bz * sA;
    B += (long)bz * sB;
    rowsum += (long)bz * sL;

    const int wr = (wave >> 1) * (BM / 2);
    const int wc = (wave & 1) * 64;
    const int fm = lane & 15;
    const int q4 = lane >> 4;
    const int sw = fm & 7;
    const int rd0 = ((q4 ^ sw) << 3);
    const int rd1 = (((4 + q4) ^ sw) << 3);

    f32x4 zero = {0.f, 0.f, 0.f, 0.f};
    f32x4 acc[MI][4];
#pragma unroll
    for (int i = 0; i < MI; i++)
#pragma unroll
        for (int j = 0; j < 4; j++) acc[i][j] = zero;

    for (int k0 = 0; k0 < K; k0 += 64) {
#pragma unroll
        for (int t = 0; t < BM / 32; t++) {
            int c = tid + t * 256;
            int row = c >> 3;
            int q = (((c & 7) ^ (row & 7)) << 3);
            gld_lds16(A + (long)(m0 + row) * lda + k0 + q, As + c * 8);
        }
#pragma unroll
        for (int t = 0; t < 4; t++) {
            int c = tid + t * 256;
            int row = c >> 3;
            int q = (((c & 7) ^ (row & 7)) << 3);
            gld_lds16(B + (long)(n0 + row) * ldb + k0 + q, Bs + c * 8);
        }
        __syncthreads();
#pragma unroll
        for (int kh = 0; kh < 2; kh++) {
            const int rdo = kh ? rd1 : rd0;
            bf16x8 af[MI], bfr[4];
#pragma unroll
            for (int i = 0; i < MI; i++)
                af[i] = *(const bf16x8*)(As + (wr + i * 16 + fm) * 64 + rdo);
#pragma unroll
            for (int j = 0; j < 4; j++)
                bfr[j] = *(const bf16x8*)(Bs + (wc + j * 16 + fm) * 64 + rdo);
#pragma unroll
            for (int i = 0; i < MI; i++)
#pragma unroll
                for (int j = 0; j < 4; j++)
                    acc[i][j] = __builtin_amdgcn_mfma_f32_16x16x32_bf16(
                        af[i], bfr[j], acc[i][j], 0, 0, 0);
        }
        __syncthreads();
    }

#pragma unroll
    for (int i = 0; i < MI; i++)
#pragma unroll
        for (int r = 0; r < 4; r++) {
            const int grow = m0 + wr + q4 * 4 + i * 16 + r;
            if constexpr (EPI == 0) {
#pragma unroll
                for (int j = 0; j < 4; j++) {
                    int gcol = n0 + wc + j * 16 + fm;
                    ((bf16*)Cout)[(long)bz * sC + (long)grow * ldc + gcol] =
                        __float2bfloat16(acc[i][j][r] + bias[gcol]);
                }
            } else if constexpr (EPI == 1) {
                float s = 0.f;
#pragma unroll
                for (int j = 0; j < 4; j++) {
                    int gcol = n0 + wc + j * 16 + fm;
                    float v = __expf(acc[i][j][r] * scale);
                    bf16 hv = __float2bfloat16(v);
                    ((bf16*)Cout)[(long)bz * sC + (long)grow * ldc + gcol] = hv;
                    s += __bfloat162float(hv);
                }
                s += __shfl_xor(s, 1, 16);
                s += __shfl_xor(s, 2, 16);
                s += __shfl_xor(s, 4, 16);
                s += __shfl_xor(s, 8, 16);
                if (fm == 0) atomicAdd(rowsum + grow, s);
            } else if constexpr (EPI == 2) {
                float inv = 1.0f / rowsum[grow];
#pragma unroll
                for (int j = 0; j < 4; j++) {
                    int gcol = n0 + wc + j * 16 + fm;
                    ((bf16*)Cout)[(long)bz * sC + (long)grow * ldc + gcol] =
                        __float2bfloat16(acc[i][j][r] * inv);
                }
            } else {
#pragma unroll
                for (int j = 0; j < 4; j++) {
                    int gcol = n0 + wc + j * 16 + fm;
                    ((float*)Cout)[(long)bz * sC + (long)grow * ldc + gcol] =
                        acc[i][j][r] + bias[gcol];
                }
            }
        }
}

// ======================================================================
// 256x256 8-phase pipelined NT GEMM (T3+T4 counted vmcnt + T5 setprio).
// r3 fix: LDS double-buffers are EIGHT DISTINCT static arrays and the tile
// loop is unrolled x2 so buffer selection is compile-time. r0-r2 used
// As[2][2] with runtime indices: the waitcnt pass cannot disambiguate
// ds_reads of buf[c] from in-flight global_load_lds DMA writes to buf[n],
// so it inserted conservative vmcnt(0) drains every phase — serializing
// the pipeline (8250 cyc/K-tile observed vs ~1000 expected; explains the
// r1->r2 null: bank conflicts were hidden under the drain). Distinct
// __restrict__ arrays give static no-alias -> only our positional vmcnt(4)
// waits remain.
// vmcnt bookkeeping (per thread, 2 loads per stage): steady entry = 4
// outstanding (this tile kh1). P1 +2, P2 +2 -> 8, VM4 drains this-kh1.
// P3 +2, P4 +2 -> 8, VM4 drains next-kh0. Last tile: VM0 drains kh1.
// LDS swizzle (r1, verified conflict-free): slot = chunk ^ ((row>>1)&3);
// global source pre-swizzled (rule #21), LDS dest linear, read offset is
// the per-thread constant ((q4 ^ ((fm>>1)&3)) << 3).
// ======================================================================
__device__ __forceinline__ void stage_half(const bf16* __restrict__ g, int ld,
                                           bf16* __restrict__ l, int tid) {
#pragma unroll
    for (int t = 0; t < 2; t++) {
        const int ch = tid + t * 512;                  // 1024 chunks of 16B
        const int row = ch >> 2;
        const int q = (ch ^ (row >> 1)) & 3;           // inverse swizzle on src
        gld_lds16(g + (long)row * ld + (q << 3), l + ch * 8);
    }
    asm volatile("" ::: "memory");  // pin issue order vs counted s_waitcnt
}

__device__ __forceinline__ void ds_a4(bf16x8 (&d)[4], const bf16* __restrict__ base,
                                      int ro, int wr, int fm, int rdo) {
#pragma unroll
    for (int i = 0; i < 4; i++)
        d[i] = *(const bf16x8*)(base + (wr + ro + i * 16 + fm) * 32 + rdo);
}

__device__ __forceinline__ void ds_b4(bf16x8 (&d)[4], const bf16* __restrict__ base,
                                      int wc, int fm, int rdo) {
#pragma unroll
    for (int j = 0; j < 4; j++)
        d[j] = *(const bf16x8*)(base + (wc + j * 16 + fm) * 32 + rdo);
}

template <int IO>
__device__ __forceinline__ void mfma16(f32x4 (&acc)[8][4], const bf16x8 (&a)[4],
                                       const bf16x8 (&b)[4]) {
    __builtin_amdgcn_s_setprio(1);
#pragma unroll
    for (int i = 0; i < 4; i++)
#pragma unroll
        for (int j = 0; j < 4; j++)
            acc[IO + i][j] = __builtin_amdgcn_mfma_f32_16x16x32_bf16(
                a[i], b[j], acc[IO + i][j], 0, 0, 0);
    __builtin_amdgcn_s_setprio(0);
}

#define BAR() __builtin_amdgcn_s_barrier()
#define VM4() asm volatile("s_waitcnt vmcnt(4)" ::: "memory")
#define VM0() asm volatile("s_waitcnt vmcnt(0)" ::: "memory")

// one K-tile (K=64): 4 phases, reads cur bufs, prefetches kn into nxt bufs
template <bool LAST>
__device__ __forceinline__ void ktile(
    f32x4 (&acc)[8][4],
    const bf16* __restrict__ Agl, int lda,
    const bf16* __restrict__ Bgl, int ldb, int kn,
    const bf16* __restrict__ cA0, const bf16* __restrict__ cB0,
    const bf16* __restrict__ cA1, const bf16* __restrict__ cB1,
    bf16* __restrict__ nA0, bf16* __restrict__ nB0,
    bf16* __restrict__ nA1, bf16* __restrict__ nB1,
    int tid, int wr, int wc, int fm, int rdo) {
    bf16x8 a[4], b[4];
    // P1: kh0, M-frags 0-3; prefetch A-kh0(next)
    ds_a4(a, cA0, 0, wr, fm, rdo);
    ds_b4(b, cB0, wc, fm, rdo);
    if constexpr (!LAST) stage_half(Agl + kn, lda, nA0, tid);
    BAR();
    mfma16<0>(acc, a, b);
    BAR();
    // P2: kh0, M-frags 4-7 (b reused); prefetch B-kh0(next)
    ds_a4(a, cA0, 64, wr, fm, rdo);
    if constexpr (!LAST) stage_half(Bgl + kn, ldb, nB0, tid);
    BAR();
    mfma16<4>(acc, a, b);
    if constexpr (!LAST) VM4(); else VM0();   // kh1(cur) landed
    BAR();
    // P3: kh1, M-frags 0-3; prefetch A-kh1(next)
    ds_a4(a, cA1, 0, wr, fm, rdo);
    ds_b4(b, cB1, wc, fm, rdo);
    if constexpr (!LAST) stage_half(Agl + kn + 32, lda, nA1, tid);
    BAR();
    mfma16<0>(acc, a, b);
    BAR();
    // P4: kh1, M-frags 4-7; prefetch B-kh1(next)
    ds_a4(a, cA1, 64, wr, fm, rdo);
    if constexpr (!LAST) stage_half(Bgl + kn + 32, ldb, nB1, tid);
    BAR();
    mfma16<4>(acc, a, b);
    if constexpr (!LAST) {
        VM4();   // kh0(next) landed
        BAR();
    }
}

template <int EPI>
__global__ __launch_bounds__(512, 2) void gemm8(
    const bf16* __restrict__ A, int lda, long sA,
    const bf16* __restrict__ B, int ldb, long sB,
    void* __restrict__ Cout, int ldc, long sC,
    int K, const float* __restrict__ bias,
    float* __restrict__ rowsum, int sL, float scale) {
    // 8 distinct arrays (16 KiB each, 128 KiB total) for static no-alias
    __shared__ __align__(16) bf16 A0h0[256 * 32], A0h1[256 * 32];
    __shared__ __align__(16) bf16 A1h0[256 * 32], A1h1[256 * 32];
    __shared__ __align__(16) bf16 B0h0[256 * 32], B0h1[256 * 32];
    __shared__ __align__(16) bf16 B1h0[256 * 32], B1h1[256 * 32];
    const int tid = threadIdx.x;
    const int lane = tid & 63;
    const int wave = tid >> 6;
    const int bz = blockIdx.z;
    const int m0 = blockIdx.x * 256, n0 = blockIdx.y * 256;
    A += (long)bz * sA + (long)m0 * lda;
    B += (long)bz * sB + (long)n0 * ldb;
    rowsum += (long)bz * sL;

    const int wm = wave >> 2, wn = wave & 3;   // 2M x 4N waves
    const int wr = wm * 128, wc = wn * 64;     // per-wave C block 128x64
    const int fm = lane & 15, q4 = lane >> 4;
    const int rdo = ((q4 ^ ((fm >> 1) & 3)) << 3);

    f32x4 zero = {0.f, 0.f, 0.f, 0.f};
    f32x4 acc[8][4];
#pragma unroll
    for (int i = 0; i < 8; i++)
#pragma unroll
        for (int j = 0; j < 4; j++) acc[i][j] = zero;

    const int NT = K >> 6;   // even (16 or 64) at every call site
    // prologue: tile 0 into buf0; wait kh0 pair (oldest 4 loads)
    stage_half(A, lda, A0h0, tid);
    stage_half(B, ldb, B0h0, tid);
    stage_half(A + 32, lda, A0h1, tid);
    stage_half(B + 32, ldb, B0h1, tid);
    VM4();
    BAR();

    int t = 0;
    for (; t + 2 < NT; t += 2) {
        ktile<false>(acc, A, lda, B, ldb, (t + 1) << 6,
                     A0h0, B0h0, A0h1, B0h1, A1h0, B1h0, A1h1, B1h1,
                     tid, wr, wc, fm, rdo);
        ktile<false>(acc, A, lda, B, ldb, (t + 2) << 6,
                     A1h0, B1h0, A1h1, B1h1, A0h0, B0h0, A0h1, B0h1,
                     tid, wr, wc, fm, rdo);
    }
    // t == NT-2: tile NT-2 on buf0 prefetching tile NT-1; last tile on buf1
    ktile<false>(acc, A, lda, B, ldb, (NT - 1) << 6,
                 A0h0, B0h0, A0h1, B0h1, A1h0, B1h0, A1h1, B1h1,
                 tid, wr, wc, fm, rdo);
    ktile<true>(acc, A, lda, B, ldb, 0,
                A1h0, B1h0, A1h1, B1h1, A0h0, B0h0, A0h1, B0h1,
                tid, wr, wc, fm, rdo);

    // C/D layout: col = lane&15, row = (lane>>4)*4 + reg  [m89/m91]
#pragma unroll
    for (int mi = 0; mi < 8; mi++)
#pragma unroll
        for (int r = 0; r < 4; r++) {
            const int grow = m0 + wr + mi * 16 + q4 * 4 + r;
            if constexpr (EPI == 0) {
#pragma unroll
                for (int j = 0; j < 4; j++) {
                    int gcol = n0 + wc + j * 16 + fm;
                    ((bf16*)Cout)[(long)bz * sC + (long)grow * ldc + gcol] =
                        __float2bfloat16(acc[mi][j][r] + bias[gcol]);
                }
            } else if constexpr (EPI == 1) {
                float s = 0.f;
#pragma unroll
                for (int j = 0; j < 4; j++) {
                    int gcol = n0 + wc + j * 16 + fm;
                    float v = __expf(acc[mi][j][r] * scale);
                    bf16 hv = __float2bfloat16(v);
                    ((bf16*)Cout)[(long)bz * sC + (long)grow * ldc + gcol] = hv;
                    s += __bfloat162float(hv);  // sum what we actually stored
                }
                s += __shfl_xor(s, 1, 16);
                s += __shfl_xor(s, 2, 16);
                s += __shfl_xor(s, 4, 16);
                s += __shfl_xor(s, 8, 16);
                if (fm == 0) atomicAdd(rowsum + grow, s);
            } else if constexpr (EPI == 2) {
                float inv = 1.0f / rowsum[grow];
#pragma unroll
                for (int j = 0; j < 4; j++) {
                    int gcol = n0 + wc + j * 16 + fm;
                    ((bf16*)Cout)[(long)bz * sC + (long)grow * ldc + gcol] =
                        __float2bfloat16(acc[mi][j][r] * inv);
                }
            } else {
#pragma unroll
                for (int j = 0; j < 4; j++) {
                    int gcol = n0 + wc + j * 16 + fm;
                    ((float*)Cout)[(long)bz * sC + (long)grow * ldc + gcol] =
                        acc[mi][j][r] + bias[gcol];
                }
            }
        }
}

extern "C" void kernel_launch(void* const* d_in, const int* in_sizes, int n_in,
                              void* d_out, int out_size, void* d_ws, size_t ws_size,
                              hipStream_t stream) {
    const float* x  = (const float*)d_in[0];
    const float* wq = (const float*)d_in[1];
    const float* bq = (const float*)d_in[2];
    const float* wk = (const float*)d_in[3];
    const float* bk = (const float*)d_in[4];
    const float* wv = (const float*)d_in[5];
    const float* bv = (const float*)d_in[6];
    const float* wo = (const float*)d_in[7];
    const float* bo = (const float*)d_in[8];
    (void)in_sizes; (void)n_in; (void)out_size;

    // base ws carve: 104.07 MiB (proven to fit)
    char* p = (char*)d_ws;
    bf16* Wc  = (bf16*)p;  p += (long)N3_ * D_ * 2;   // 6 MiB
    bf16* Wo  = (bf16*)p;  p += (long)D_ * D_ * 2;    // 2 MiB
    float* bc = (float*)p; p += N3_ * 4;              // 12 KiB
    bf16* QKV = (bf16*)p;  p += (long)BS_ * N3_ * 2;  // 96 MiB; Q cols become At
    float* ls = (float*)p; p += (long)BS_ * 4;        // 64 KiB

    bf16* xb = (bf16*)d_out;                          // 32 MiB; dead after QKV GEMM

    const size_t base = 109129728UL;
    int tier;
    bf16 *VT, *E;
    if (ws_size >= base + 134217728UL) {
        tier = 2;
        E  = (bf16*)p;
        VT = (bf16*)((char*)d_out + 33554432);
    } else if (ws_size >= base + 33554432UL) {
        tier = 1;
        VT = (bf16*)p;
        E  = (bf16*)d_out;
    } else {
        tier = 0;
        VT = (bf16*)((char*)d_out + 33554432);
        E  = (bf16*)d_out;
    }

    // 1) fused prologue
    prologue<<<dim3(20545), 256, 0, stream>>>(x, wq, wk, wv, wo, bq, bk, bv,
                                              xb, Wc, Wo, bc, ls);

    // 2) QKV = xb @ Wc^T + bc  (M=16384, N=3072, K=1024) — 256^2 8-phase
    gemm8<0><<<dim3(BS_ / 256, N3_ / 256, 1), 512, 0, stream>>>(
        xb, D_, 0, Wc, D_, 0, QKV, N3_, 0, D_, bc, ls, 0, 1.f);

    // 3) VT[b][d][s] = V[b][s][d]
    transpose_v<<<dim3(S_ / 32, D_ / 32, B_), 256, 0, stream>>>(QKV, VT);

    // 4) attention: E = exp(QK^T/32) (+rowsum), At = (E V)/rowsum -> Q region
    if (tier == 2) {
        gemm8<1><<<dim3(16, 16, 4), 512, 0, stream>>>(
            QKV, N3_, (long)S_ * N3_, QKV + 1024, N3_, (long)S_ * N3_,
            E, S_, (long)S_ * S_, D_, nullptr, ls, S_, 0.03125f);
        gemm8<2><<<dim3(16, 4, 4), 512, 0, stream>>>(
            E, S_, (long)S_ * S_, VT, S_, (long)D_ * S_,
            QKV, N3_, (long)S_ * N3_, S_, nullptr, ls, S_, 1.f);
    } else if (tier == 1) {
        for (int pr = 0; pr < 2; ++pr) {
            const long qoff = (long)(2 * pr) * S_ * N3_;
            gemm_nt<1, 128><<<dim3(32, 32, 2), 256, 0, stream>>>(
                QKV + qoff, N3_, (long)S_ * N3_,
                QKV + qoff + 1024, N3_, (long)S_ * N3_,
                E, S_, (long)S_ * S_, D_, nullptr, ls + 2 * pr * S_, S_, 0.03125f);
            gemm_nt<2, 128><<<dim3(32, 8, 2), 256, 0, stream>>>(
                E, S_, (long)S_ * S_,
                VT + (long)(2 * pr) * D_ * S_, S_, (long)D_ * S_,
                QKV + qoff, N3_, (long)S_ * N3_, S_, nullptr, ls + 2 * pr * S_, S_, 1.f);
        }
    } else {
        for (int b = 0; b < B_; ++b) {
            const long qoff = (long)b * S_ * N3_;
            gemm_nt<1, 128><<<dim3(32, 32, 1), 256, 0, stream>>>(
                QKV + qoff, N3_, 0, QKV + qoff + 1024, N3_, 0,
                E, S_, 0, D_, nullptr, ls + b * S_, 0, 0.03125f);
            gemm_nt<2, 64><<<dim3(64, 8, 1), 256, 0, stream>>>(
                E, S_, 0, VT + (long)b * D_ * S_, S_, 0,
                QKV + qoff, N3_, 0, S_, nullptr, ls + b * S_, 0, 1.f);
        }
    }

    // 5) out = At @ Wo^T + bo -> fp32  (M=16384, N=1024, K=1024)
    gemm8<3><<<dim3(BS_ / 256, D_ / 256, 1), 512, 0, stream>>>(
        QKV, N3_, 0, Wo, D_, 0, d_out, D_, 0, D_, bo, ls, 0, 1.f);
}